// Round 1
// baseline (759.272 us; speedup 1.0000x reference)
//
#include <hip/hip_runtime.h>
#include <stdint.h>
#include <math.h>

typedef __attribute__((ext_vector_type(4))) float  f32x4;
typedef __attribute__((ext_vector_type(8))) short  bf16x8;
typedef __attribute__((ext_vector_type(4))) short  s16x4;

#define AS1 __attribute__((address_space(1)))
#define AS3 __attribute__((address_space(3)))

// async global->LDS, 16B per lane; lds must be wave-uniform base (HW adds lane*16)
static __device__ __forceinline__ void async_ld16(void* lds, const void* g) {
  __builtin_amdgcn_global_load_lds((const AS1 uint32_t*)g, (AS3 uint32_t*)lds, 16, 0, 0);
}

static __device__ __forceinline__ float bf2f(short u) {
  union { uint32_t i; float f; } v; v.i = ((uint32_t)(uint16_t)u) << 16; return v.f;
}
static __device__ __forceinline__ short f2bf(float f) {  // round-to-nearest-even
  union { float f; uint32_t i; } v; v.f = f;
  uint32_t x = v.i;
  return (short)((x + 0x7fffu + ((x >> 16) & 1u)) >> 16);
}

// ---------------- trig table: ct/st[pos*32 + i], f64 like numpy promotion ----
__global__ __launch_bounds__(256) void k_trig(float* __restrict__ ct, float* __restrict__ st) {
  int idx = blockIdx.x * 256 + threadIdx.x;          // 8192*32 = 262144
  int pos = idx >> 5, i = idx & 31;
  double invf = 1.0 / pow(10000.0, (double)(2 * i) / 64.0);
  float f = (float)((double)pos * invf);
  ct[idx] = cosf(f);
  st[idx] = sinf(f);
}

// ---------------- fp32 (K x N) -> bf16 transposed (N x K) -------------------
__global__ __launch_bounds__(256) void k_transpose_cvt(const float* __restrict__ in,
                                                       short* __restrict__ out, int K, int N) {
  __shared__ float tile[64][65];
  int n0 = blockIdx.x * 64, k0 = blockIdx.y * 64;
  int tid = threadIdx.x;
  #pragma unroll
  for (int it = 0; it < 16; ++it) {
    int idx = tid + it * 256;
    int r = idx >> 6, c = idx & 63;                  // r: k-offset, c: n-offset
    tile[r][c] = in[(size_t)(k0 + r) * N + (n0 + c)];
  }
  __syncthreads();
  #pragma unroll
  for (int it = 0; it < 16; ++it) {
    int idx = tid + it * 256;
    int r = idx >> 6, c = idx & 63;                  // r: n-offset, c: k-offset
    out[(size_t)(n0 + r) * K + (k0 + c)] = f2bf(tile[c][r]);
  }
}

// ---------------- RMSNorm: fp32 in -> bf16 out ------------------------------
__global__ __launch_bounds__(256) void k_rmsnorm(const float* __restrict__ x,
                                                 const float* __restrict__ w,
                                                 short* __restrict__ xn) {
  int row = blockIdx.x;
  const float* xr = x + (size_t)row * 1024;
  int tid = threadIdx.x;
  f32x4 v = *(const f32x4*)(xr + (tid << 2));
  float ss = v[0]*v[0] + v[1]*v[1] + v[2]*v[2] + v[3]*v[3];
  #pragma unroll
  for (int off = 1; off < 64; off <<= 1) ss += __shfl_xor(ss, off);
  __shared__ float red[4];
  if ((tid & 63) == 0) red[tid >> 6] = ss;
  __syncthreads();
  float tot = red[0] + red[1] + red[2] + red[3];
  float inv = rsqrtf(tot * (1.0f / 1024.0f) + 1.1920928955078125e-07f);
  f32x4 wv = *(const f32x4*)(w + (tid << 2));
  s16x4 o;
  #pragma unroll
  for (int e = 0; e < 4; ++e) o[e] = f2bf(v[e] * inv * wv[e]);
  *(s16x4*)(xn + (size_t)row * 1024 + (tid << 2)) = o;
}

// ---------------- bf16 GEMM: C(MxN) = A(MxK) * Bt(NxK)^T --------------------
// 128x128 tile, BK=32, 4 waves, 64x64 per wave, mfma_f32_16x16x32_bf16.
// LDS seg-swizzle: slot(row, s) holds global 8-elem seg (s ^ ((row>>1)&3)).
template<bool OUT_BF16>
__global__ __launch_bounds__(256) void k_gemm(const short* __restrict__ A,
                                              const short* __restrict__ Bt,
                                              void* __restrict__ Cout,
                                              int M, int N, int K) {
  __shared__ short As[128 * 32];
  __shared__ short Bs[128 * 32];
  const int tid = threadIdx.x;
  const int wave = tid >> 6, lane = tid & 63;
  const int g = lane >> 4, r = lane & 15;

  // XCD-aware swizzle (nwg % 8 == 0 for both launches)
  const int nwg = gridDim.x, bid = blockIdx.x;
  const int cpx = nwg >> 3;
  const int swz = (bid & 7) * cpx + (bid >> 3);
  const int nbx = N >> 7;
  const int bx = swz % nbx, by = swz / nbx;
  const int m0 = by << 7, n0 = bx << 7;
  const int wr = wave >> 1, wc = wave & 1;

  f32x4 acc[4][4];
  #pragma unroll
  for (int i = 0; i < 4; ++i)
    #pragma unroll
    for (int j = 0; j < 4; ++j)
      #pragma unroll
      for (int e = 0; e < 4; ++e) acc[i][j][e] = 0.0f;

  // staging chunks: i in [0,512): row=i>>2, seg=i&3, src seg = seg ^ ((row>>1)&3)
  const int ci0 = wave * 128 + lane, ci1 = ci0 + 64;
  const int ar0 = ci0 >> 2, as0 = (ci0 & 3) ^ ((ar0 >> 1) & 3);
  const int ar1 = ci1 >> 2, as1 = (ci1 & 3) ^ ((ar1 >> 1) & 3);
  const short* Ag0 = A  + (size_t)(m0 + ar0) * K + as0 * 8;
  const short* Ag1 = A  + (size_t)(m0 + ar1) * K + as1 * 8;
  const short* Bg0 = Bt + (size_t)(n0 + ar0) * K + as0 * 8;
  const short* Bg1 = Bt + (size_t)(n0 + ar1) * K + as1 * 8;
  short* Al0 = &As[(wave * 128 + 0)  * 8];
  short* Al1 = &As[(wave * 128 + 64) * 8];
  short* Bl0 = &Bs[(wave * 128 + 0)  * 8];
  short* Bl1 = &Bs[(wave * 128 + 64) * 8];

  for (int k0 = 0; k0 < K; k0 += 32) {
    async_ld16(Al0, Ag0 + k0);
    async_ld16(Al1, Ag1 + k0);
    async_ld16(Bl0, Bg0 + k0);
    async_ld16(Bl1, Bg1 + k0);
    __syncthreads();   // drains vmcnt before barrier (compiler-inserted)
    bf16x8 af[4], bfr[4];
    #pragma unroll
    for (int m = 0; m < 4; ++m) {
      int row = wr * 64 + m * 16 + r;
      af[m] = *(const bf16x8*)&As[row * 32 + ((g ^ ((row >> 1) & 3)) * 8)];
    }
    #pragma unroll
    for (int n = 0; n < 4; ++n) {
      int row = wc * 64 + n * 16 + r;
      bfr[n] = *(const bf16x8*)&Bs[row * 32 + ((g ^ ((row >> 1) & 3)) * 8)];
    }
    #pragma unroll
    for (int m = 0; m < 4; ++m)
      #pragma unroll
      for (int n = 0; n < 4; ++n)
        acc[m][n] = __builtin_amdgcn_mfma_f32_16x16x32_bf16(af[m], bfr[n], acc[m][n], 0, 0, 0);
    __syncthreads();
  }

  if (OUT_BF16) {
    short* C = (short*)Cout;
    #pragma unroll
    for (int m = 0; m < 4; ++m) {
      int rowb = m0 + wr * 64 + m * 16 + g * 4;
      #pragma unroll
      for (int n = 0; n < 4; ++n) {
        int col = n0 + wc * 64 + n * 16 + r;
        #pragma unroll
        for (int q = 0; q < 4; ++q) C[(size_t)(rowb + q) * N + col] = f2bf(acc[m][n][q]);
      }
    }
  } else {
    float* C = (float*)Cout;
    #pragma unroll
    for (int m = 0; m < 4; ++m) {
      int rowb = m0 + wr * 64 + m * 16 + g * 4;
      #pragma unroll
      for (int n = 0; n < 4; ++n) {
        int col = n0 + wc * 64 + n * 16 + r;
        #pragma unroll
        for (int q = 0; q < 4; ++q) C[(size_t)(rowb + q) * N + col] = acc[m][n][q];
      }
    }
  }
}

// ---------------- RoPE in-place on q,k parts of qkv (bf16) ------------------
__global__ __launch_bounds__(256) void k_rope(short* __restrict__ qkv,
                                              const float* __restrict__ ct,
                                              const float* __restrict__ st) {
  int t = blockIdx.x * 256 + threadIdx.x;            // 32768*128 tasks
  int row = t >> 7, rem = t & 127;
  int hp = rem >> 2, d0 = (rem & 3) * 8;
  int part = hp >> 4, h = hp & 15;
  size_t base = (size_t)row * 3072 + part * 1024 + h * 64;
  int pos = row & 8191;
  bf16x8 lo = *(const bf16x8*)(qkv + base + d0);
  bf16x8 hi = *(const bf16x8*)(qkv + base + d0 + 32);
  f32x4 c0 = *(const f32x4*)(ct + pos * 32 + d0);
  f32x4 c1 = *(const f32x4*)(ct + pos * 32 + d0 + 4);
  f32x4 s0 = *(const f32x4*)(st + pos * 32 + d0);
  f32x4 s1 = *(const f32x4*)(st + pos * 32 + d0 + 4);
  bf16x8 olo, ohi;
  #pragma unroll
  for (int e = 0; e < 8; ++e) {
    float c = (e < 4) ? c0[e & 3] : c1[e & 3];
    float s = (e < 4) ? s0[e & 3] : s1[e & 3];
    float xl = bf2f(lo[e]), xh = bf2f(hi[e]);
    olo[e] = f2bf(xl * c - xh * s);
    ohi[e] = f2bf(xh * c + xl * s);
  }
  *(bf16x8*)(qkv + base + d0) = olo;
  *(bf16x8*)(qkv + base + d0 + 32) = ohi;
}

// ---------------- sliding-window attention ----------------------------------
// 1 block (256 thr, 4 waves) per (win, h, b). Q 64x64, Kcat/Vcat 128x64.
// key j valid iff j in [i, i+64] (and j>=64 for win 0). scale folded post-MFMA.
__global__ __launch_bounds__(256) void k_attn(const short* __restrict__ qkv,
                                              short* __restrict__ aout) {
  const int win = blockIdx.x, h = blockIdx.y, bb = blockIdx.z;
  __shared__ short Qs[64 * 64];     // slot(row,s8)  <- global seg s^(row&7)
  __shared__ short Ks[128 * 64];    // slot(j,s8)    <- global seg s^(j&7)
  __shared__ short Vt[64 * 128];    // [d][key], slot(d,s16) <- key-seg s^(d&15)
  __shared__ short Ps[64 * 128];    // [q][key], slot(i,s16) <- key-seg s^(i&15)

  const int tid = threadIdx.x;
  const int wave = tid >> 6, lane = tid & 63;
  const int g = lane >> 4, r = lane & 15;
  const size_t bbase = (size_t)bb * 8192;

  // stage Q (512 chunks)
  #pragma unroll
  for (int t = 0; t < 2; ++t) {
    int i = wave * 128 + t * 64 + lane;
    int row = i >> 3, seg = i & 7;
    int sseg = seg ^ (row & 7);
    const short* gp = qkv + (bbase + win * 64 + row) * 3072 + h * 64 + sseg * 8;
    async_ld16(&Qs[(wave * 128 + t * 64) * 8], gp);
  }
  // stage K (1024 chunks)
  #pragma unroll
  for (int t = 0; t < 4; ++t) {
    int i = wave * 256 + t * 64 + lane;
    int row = i >> 3, seg = i & 7;
    int sseg = seg ^ (row & 7);
    int kpos = win * 64 - 64 + row; if (kpos < 0) kpos = 0;
    const short* gp = qkv + (bbase + kpos) * 3072 + 1024 + h * 64 + sseg * 8;
    async_ld16(&Ks[(wave * 256 + t * 64) * 8], gp);
  }
  // stage V transposed (reg-staged)
  #pragma unroll
  for (int t = 0; t < 4; ++t) {
    int task = tid + t * 256;
    int j = task >> 3, dseg = task & 7;
    int kpos = win * 64 - 64 + j; if (kpos < 0) kpos = 0;
    bf16x8 v = *(const bf16x8*)(qkv + (bbase + kpos) * 3072 + 2048 + h * 64 + dseg * 8);
    #pragma unroll
    for (int e = 0; e < 8; ++e) {
      int d = dseg * 8 + e;
      Vt[d * 128 + (((j >> 3) ^ (d & 15)) * 8) + (j & 7)] = v[e];
    }
  }
  __syncthreads();

  // ---- S = Q K^T for this wave's 16-query strip
  f32x4 sac[8];
  #pragma unroll
  for (int n = 0; n < 8; ++n)
    #pragma unroll
    for (int e = 0; e < 4; ++e) sac[n][e] = 0.0f;
  {
    bf16x8 aq[2];
    #pragma unroll
    for (int ks = 0; ks < 2; ++ks) {
      int row = wave * 16 + r;
      aq[ks] = *(const bf16x8*)&Qs[row * 64 + (((ks * 4 + g) ^ (row & 7)) * 8)];
    }
    #pragma unroll
    for (int n = 0; n < 8; ++n)
      #pragma unroll
      for (int ks = 0; ks < 2; ++ks) {
        int key = n * 16 + r;
        bf16x8 bk = *(const bf16x8*)&Ks[key * 64 + (((ks * 4 + g) ^ (key & 7)) * 8)];
        sac[n] = __builtin_amdgcn_mfma_f32_16x16x32_bf16(aq[ks], bk, sac[n], 0, 0, 0);
      }
  }

  // ---- masked softmax (rows i = wave*16 + g*4 + q; cols j = n*16 + r)
  float pm[8][4], mx[4], sm[4];
  #pragma unroll
  for (int q = 0; q < 4; ++q) mx[q] = -3.0e38f;
  #pragma unroll
  for (int n = 0; n < 8; ++n)
    #pragma unroll
    for (int q = 0; q < 4; ++q) {
      int iq = wave * 16 + g * 4 + q;
      int j = n * 16 + r;
      bool ok = (j >= iq) && (j <= iq + 64) && (win > 0 || j >= 64);
      float s = ok ? sac[n][q] * 0.125f : -3.0e38f;
      pm[n][q] = s;
      mx[q] = fmaxf(mx[q], s);
    }
  #pragma unroll
  for (int q = 0; q < 4; ++q)
    #pragma unroll
    for (int off = 1; off < 16; off <<= 1) mx[q] = fmaxf(mx[q], __shfl_xor(mx[q], off));
  #pragma unroll
  for (int q = 0; q < 4; ++q) sm[q] = 0.0f;
  #pragma unroll
  for (int n = 0; n < 8; ++n)
    #pragma unroll
    for (int q = 0; q < 4; ++q) {
      float p = __expf(pm[n][q] - mx[q]);
      pm[n][q] = p;
      sm[q] += p;
    }
  #pragma unroll
  for (int q = 0; q < 4; ++q) {
    #pragma unroll
    for (int off = 1; off < 16; off <<= 1) sm[q] += __shfl_xor(sm[q], off);
    sm[q] = 1.0f / sm[q];
  }
  #pragma unroll
  for (int n = 0; n < 8; ++n)
    #pragma unroll
    for (int q = 0; q < 4; ++q) {
      int iq = wave * 16 + g * 4 + q;
      int j = n * 16 + r;
      Ps[iq * 128 + (((j >> 3) ^ (iq & 15)) * 8) + (j & 7)] = f2bf(pm[n][q] * sm[q]);
    }
  __syncthreads();   // safety: P/V visibility before PV reads

  // ---- O = P V
  f32x4 oac[4];
  #pragma unroll
  for (int n = 0; n < 4; ++n)
    #pragma unroll
    for (int e = 0; e < 4; ++e) oac[n][e] = 0.0f;
  #pragma unroll
  for (int ks = 0; ks < 4; ++ks) {
    int rowp = wave * 16 + r;
    bf16x8 ap = *(const bf16x8*)&Ps[rowp * 128 + (((ks * 4 + g) ^ (rowp & 15)) * 8)];
    #pragma unroll
    for (int n = 0; n < 4; ++n) {
      int d = n * 16 + r;
      bf16x8 bv = *(const bf16x8*)&Vt[d * 128 + (((ks * 4 + g) ^ (d & 15)) * 8)];
      oac[n] = __builtin_amdgcn_mfma_f32_16x16x32_bf16(ap, bv, oac[n], 0, 0, 0);
    }
  }
  #pragma unroll
  for (int n = 0; n < 4; ++n)
    #pragma unroll
    for (int q = 0; q < 4; ++q) {
      int iq = wave * 16 + g * 4 + q;
      int d = n * 16 + r;
      int pos = win * 64 + iq;
      aout[(bbase + pos) * 1024 + h * 64 + d] = f2bf(oac[n][q]);
    }
}

extern "C" void kernel_launch(void* const* d_in, const int* in_sizes, int n_in,
                              void* d_out, int out_size, void* d_ws, size_t ws_size,
                              hipStream_t stream) {
  const float* x      = (const float*)d_in[0];
  const float* w_norm = (const float*)d_in[1];
  const float* w_qkv  = (const float*)d_in[2];
  const float* w_o    = (const float*)d_in[3];
  float* out = (float*)d_out;
  (void)in_sizes; (void)n_in; (void)out_size; (void)ws_size;

  const int R = 4 * 8192;  // 32768 rows

  char* ws = (char*)d_ws;
  size_t off = 0;
  auto alloc = [&](size_t bytes) { char* p = ws + off; off += (bytes + 255) & ~(size_t)255; return p; };
  short* xn   = (short*)alloc((size_t)R * 1024 * 2);
  short* wqT  = (short*)alloc((size_t)3072 * 1024 * 2);
  short* woT  = (short*)alloc((size_t)1024 * 1024 * 2);
  short* qkv  = (short*)alloc((size_t)R * 3072 * 2);
  short* aout = (short*)alloc((size_t)R * 1024 * 2);
  float* ct   = (float*)alloc((size_t)8192 * 32 * 4);
  float* st   = (float*)alloc((size_t)8192 * 32 * 4);

  k_trig<<<1024, 256, 0, stream>>>(ct, st);
  k_transpose_cvt<<<dim3(3072 / 64, 1024 / 64), 256, 0, stream>>>(w_qkv, wqT, 1024, 3072);
  k_transpose_cvt<<<dim3(1024 / 64, 1024 / 64), 256, 0, stream>>>(w_o, woT, 1024, 1024);
  k_rmsnorm<<<R, 256, 0, stream>>>(x, w_norm, xn);
  k_gemm<true><<<(R / 128) * (3072 / 128), 256, 0, stream>>>(xn, wqT, qkv, R, 3072, 1024);
  k_rope<<<16384, 256, 0, stream>>>(qkv, ct, st);
  k_attn<<<dim3(128, 16, 4), 256, 0, stream>>>(qkv, aout);
  k_gemm<false><<<(R / 128) * (1024 / 128), 256, 0, stream>>>(aout, woT, out, R, 1024, 1024);
}

// Round 3
// 608.196 us; speedup vs baseline: 1.2484x; 1.2484x over previous
//
#include <hip/hip_runtime.h>
#include <stdint.h>
#include <math.h>

typedef __attribute__((ext_vector_type(4))) float  f32x4;
typedef __attribute__((ext_vector_type(8))) short  bf16x8;
typedef __attribute__((ext_vector_type(4))) short  s16x4;

#define AS1 __attribute__((address_space(1)))
#define AS3 __attribute__((address_space(3)))

// async global->LDS, 16B per lane; lds base must be wave-uniform (HW adds lane*16)
static __device__ __forceinline__ void async_ld16(void* lds, const void* g) {
  __builtin_amdgcn_global_load_lds((const AS1 uint32_t*)g, (AS3 uint32_t*)lds, 16, 0, 0);
}

static __device__ __forceinline__ float bf2f(short u) {
  union { uint32_t i; float f; } v; v.i = ((uint32_t)(uint16_t)u) << 16; return v.f;
}
static __device__ __forceinline__ short f2bf(float f) {  // round-to-nearest-even
  union { float f; uint32_t i; } v; v.f = f;
  uint32_t x = v.i;
  return (short)((x + 0x7fffu + ((x >> 16) & 1u)) >> 16);
}

#define BAR()   __builtin_amdgcn_s_barrier()
#define LGKM0() do { asm volatile("s_waitcnt lgkmcnt(0)" ::: "memory"); \
                     __builtin_amdgcn_sched_barrier(0); } while (0)
#define VMW4()  asm volatile("s_waitcnt vmcnt(4)" ::: "memory")
#define PRIO(p) __builtin_amdgcn_s_setprio(p)

// ---------------- trig table: ct/st[pos*32 + i] -----------------------------
__global__ __launch_bounds__(256) void k_trig(float* __restrict__ ct, float* __restrict__ st) {
  int idx = blockIdx.x * 256 + threadIdx.x;          // 8192*32 = 262144
  int pos = idx >> 5, i = idx & 31;
  double invf = 1.0 / pow(10000.0, (double)(2 * i) / 64.0);
  float f = (float)((double)pos * invf);
  ct[idx] = cosf(f);
  st[idx] = sinf(f);
}

// ---------------- fp32 (K x N) -> bf16 transposed (N x K) -------------------
__global__ __launch_bounds__(256) void k_transpose_cvt(const float* __restrict__ in,
                                                       short* __restrict__ out, int K, int N) {
  __shared__ float tile[64][65];
  int n0 = blockIdx.x * 64, k0 = blockIdx.y * 64;
  int tid = threadIdx.x;
  #pragma unroll
  for (int it = 0; it < 16; ++it) {
    int idx = tid + it * 256;
    int r = idx >> 6, c = idx & 63;
    tile[r][c] = in[(size_t)(k0 + r) * N + (n0 + c)];
  }
  __syncthreads();
  #pragma unroll
  for (int it = 0; it < 16; ++it) {
    int idx = tid + it * 256;
    int r = idx >> 6, c = idx & 63;
    out[(size_t)(n0 + r) * K + (k0 + c)] = f2bf(tile[c][r]);
  }
}

// ---------------- RMSNorm: fp32 in -> bf16 out ------------------------------
__global__ __launch_bounds__(256) void k_rmsnorm(const float* __restrict__ x,
                                                 const float* __restrict__ w,
                                                 short* __restrict__ xn) {
  int row = blockIdx.x;
  const float* xr = x + (size_t)row * 1024;
  int tid = threadIdx.x;
  f32x4 v = *(const f32x4*)(xr + (tid << 2));
  float ss = v[0]*v[0] + v[1]*v[1] + v[2]*v[2] + v[3]*v[3];
  #pragma unroll
  for (int off = 1; off < 64; off <<= 1) ss += __shfl_xor(ss, off);
  __shared__ float red[4];
  if ((tid & 63) == 0) red[tid >> 6] = ss;
  __syncthreads();
  float tot = red[0] + red[1] + red[2] + red[3];
  float inv = rsqrtf(tot * (1.0f / 1024.0f) + 1.1920928955078125e-07f);
  f32x4 wv = *(const f32x4*)(w + (tid << 2));
  s16x4 o;
  #pragma unroll
  for (int e = 0; e < 4; ++e) o[e] = f2bf(v[e] * inv * wv[e]);
  *(s16x4*)(xn + (size_t)row * 1024 + (tid << 2)) = o;
}

// ---------------- bf16 GEMM 256x256x(BK=64), 8 waves, pipelined -------------
// C(MxN) = A(MxK) * Bt(NxK)^T. 2-deep LDS double buffer, counted vmcnt(4),
// XOR seg-swizzle (T2), setprio around MFMA (T5). Optional fused RoPE epilogue.
//
// Stage schedule per K-tile t (buf cur=t&1): P1: t+1.A1  P2: t+1.B1
// P3: t+2.B0 (B of cur fully read after P2)  P4: t+2.A0 (A free after P3).
// vmcnt(4) at P4-end => all but {t+2.B0, t+2.A0} landed => t+1 complete.
#define STAGE(mi, P, rb, h, kt, buf) do {                                          \
    const int lrb = (h) * 128 + wrow;                                              \
    const short* _s0 = (P) + (size_t)((rb) + lrb + srow) * K + (kt) * 64 + xseg * 8;      \
    const short* _s1 = (P) + (size_t)((rb) + lrb + 8 + srow) * K + (kt) * 64 + xseg * 8;  \
    async_ld16(&lds[buf][mi][lrb * 64], _s0);                                      \
    async_ld16(&lds[buf][mi][(lrb + 8) * 64], _s1);                                \
  } while (0)

#define RDA(buf, mh, m, kk) \
  (*(const bf16x8*)&lds[buf][0][(wr * 128 + (mh) * 64 + (m) * 16 + r) * 64 + ((((kk) * 4 + g) ^ rs) * 8)])
#define RDB(buf, nh, n, kk) \
  (*(const bf16x8*)&lds[buf][1][(wc * 64 + (nh) * 32 + (n) * 16 + r) * 64 + ((((kk) * 4 + g) ^ rs) * 8)])

template<bool OUT_BF16, bool ROPE>
__global__ __launch_bounds__(512, 2) void k_gemm2(const short* __restrict__ A,
                                                  const short* __restrict__ Bt,
                                                  void* __restrict__ Cout,
                                                  const float* __restrict__ ct,
                                                  const float* __restrict__ st,
                                                  int M, int N, int K) {
  __shared__ short lds[2][2][256 * 64];   // [buf][A/B][256 rows x 64 k] = 128 KiB
  (void)M;
  const int tid  = threadIdx.x;
  const int wave = tid >> 6, lane = tid & 63;
  const int g = lane >> 4, r = lane & 15;
  const int wr = wave >> 2, wc = wave & 3;
  const int rs = r & 7;

  const int nwg = gridDim.x, bid = blockIdx.x;
  const int cpx = nwg >> 3;
  const int swz = (bid & 7) * cpx + (bid >> 3);
  const int nbx = N >> 8;
  const int bx = swz % nbx, by = swz / nbx;
  const int m0 = by << 8, n0 = bx << 8;
  const int NT = K >> 6;

  const int srow = lane >> 3;            // row-in-8-group
  const int xseg = (lane & 7) ^ srow;    // pre-swizzled source segment
  const int wrow = wave * 16;

  f32x4 acc[8][4];
  #pragma unroll
  for (int i = 0; i < 8; ++i)
    #pragma unroll
    for (int j = 0; j < 4; ++j)
      acc[i][j] = (f32x4){0.f, 0.f, 0.f, 0.f};

  // prologue: t0 fully + t1.{B0,A0}; wait until only those 4 loads in flight
  STAGE(0, A,  m0, 0, 0, 0);
  STAGE(0, A,  m0, 1, 0, 0);
  STAGE(1, Bt, n0, 0, 0, 0);
  STAGE(1, Bt, n0, 1, 0, 0);
  STAGE(1, Bt, n0, 0, 1, 1);
  STAGE(0, A,  m0, 0, 1, 1);
  VMW4(); BAR();

  bf16x8 a[4][2], b0[2][2], b1[2][2];
  for (int t = 0; t < NT; ++t) {
    const int cur = t & 1, nxt = cur ^ 1;
    const int t1 = (t + 1 < NT) ? t + 1 : 0;
    const int t2 = (t + 2 < NT) ? t + 2 : t + 2 - NT;

    // ---- P1: read A(mh0)+B(nh0); stage t+1.A1; MFMA quad(0,0)
    #pragma unroll
    for (int m = 0; m < 4; ++m) { a[m][0] = RDA(cur, 0, m, 0); a[m][1] = RDA(cur, 0, m, 1); }
    #pragma unroll
    for (int n = 0; n < 2; ++n) { b0[n][0] = RDB(cur, 0, n, 0); b0[n][1] = RDB(cur, 0, n, 1); }
    STAGE(0, A, m0, 1, t1, nxt);
    BAR(); LGKM0(); PRIO(1);
    #pragma unroll
    for (int m = 0; m < 4; ++m)
      #pragma unroll
      for (int n = 0; n < 2; ++n)
        #pragma unroll
        for (int kk = 0; kk < 2; ++kk)
          acc[m][n] = __builtin_amdgcn_mfma_f32_16x16x32_bf16(a[m][kk], b0[n][kk], acc[m][n], 0, 0, 0);
    PRIO(0); BAR();

    // ---- P2: read B(nh1); stage t+1.B1; MFMA quad(0,1)
    #pragma unroll
    for (int n = 0; n < 2; ++n) { b1[n][0] = RDB(cur, 1, n, 0); b1[n][1] = RDB(cur, 1, n, 1); }
    STAGE(1, Bt, n0, 1, t1, nxt);
    BAR(); LGKM0(); PRIO(1);
    #pragma unroll
    for (int m = 0; m < 4; ++m)
      #pragma unroll
      for (int n = 0; n < 2; ++n)
        #pragma unroll
        for (int kk = 0; kk < 2; ++kk)
          acc[m][2 + n] = __builtin_amdgcn_mfma_f32_16x16x32_bf16(a[m][kk], b1[n][kk], acc[m][2 + n], 0, 0, 0);
    PRIO(0); BAR();

    // ---- P3: read A(mh1); stage t+2.B0 into cur; MFMA quad(1,1)
    #pragma unroll
    for (int m = 0; m < 4; ++m) { a[m][0] = RDA(cur, 1, m, 0); a[m][1] = RDA(cur, 1, m, 1); }
    STAGE(1, Bt, n0, 0, t2, cur);
    BAR(); LGKM0(); PRIO(1);
    #pragma unroll
    for (int m = 0; m < 4; ++m)
      #pragma unroll
      for (int n = 0; n < 2; ++n)
        #pragma unroll
        for (int kk = 0; kk < 2; ++kk)
          acc[4 + m][2 + n] = __builtin_amdgcn_mfma_f32_16x16x32_bf16(a[m][kk], b1[n][kk], acc[4 + m][2 + n], 0, 0, 0);
    PRIO(0); BAR();

    // ---- P4: stage t+2.A0 into cur; MFMA quad(1,0); counted vmcnt
    STAGE(0, A, m0, 0, t2, cur);
    PRIO(1);
    #pragma unroll
    for (int m = 0; m < 4; ++m)
      #pragma unroll
      for (int n = 0; n < 2; ++n)
        #pragma unroll
        for (int kk = 0; kk < 2; ++kk)
          acc[4 + m][n] = __builtin_amdgcn_mfma_f32_16x16x32_bf16(a[m][kk], b0[n][kk], acc[4 + m][n], 0, 0, 0);
    PRIO(0);
    VMW4(); BAR();
  }

  // ---- epilogue (optional fused RoPE on q,k column range) ----
  if (OUT_BF16) {
    short* C = (short*)Cout;
    const bool doRope = ROPE && (n0 < 2048);
    #pragma unroll
    for (int mi = 0; mi < 8; ++mi) {
      const int rowb = m0 + wr * 128 + mi * 16 + g * 4;
      if (doRope) {
        #pragma unroll
        for (int q = 0; q < 4; ++q) {
          const int pos = (rowb + q) & 8191;
          #pragma unroll
          for (int ni = 0; ni < 2; ++ni) {
            const float c = ct[pos * 32 + ni * 16 + r];
            const float s = st[pos * 32 + ni * 16 + r];
            const float p0 = acc[mi][ni][q], p1 = acc[mi][ni + 2][q];
            acc[mi][ni][q]     = p0 * c - p1 * s;
            acc[mi][ni + 2][q] = p1 * c + p0 * s;
          }
        }
      }
      #pragma unroll
      for (int ni = 0; ni < 4; ++ni) {
        const int col = n0 + wc * 64 + ni * 16 + r;
        #pragma unroll
        for (int q = 0; q < 4; ++q)
          C[(size_t)(rowb + q) * N + col] = f2bf(acc[mi][ni][q]);
      }
    }
  } else {
    float* C = (float*)Cout;
    #pragma unroll
    for (int mi = 0; mi < 8; ++mi) {
      const int rowb = m0 + wr * 128 + mi * 16 + g * 4;
      #pragma unroll
      for (int ni = 0; ni < 4; ++ni) {
        const int col = n0 + wc * 64 + ni * 16 + r;
        #pragma unroll
        for (int q = 0; q < 4; ++q)
          C[(size_t)(rowb + q) * N + col] = acc[mi][ni][q];
      }
    }
  }
}

// ---------------- sliding-window attention ----------------------------------
// 1 block (256 thr, 4 waves) per (win, h, b). Q 64x64, Kcat/Vcat 128x64.
// key j valid iff j in [i, i+64] (and j>=64 for win 0). scale folded post-MFMA.
__global__ __launch_bounds__(256) void k_attn(const short* __restrict__ qkv,
                                              short* __restrict__ aout) {
  const int win = blockIdx.x, h = blockIdx.y, bb = blockIdx.z;
  __shared__ short Qs[64 * 64];
  __shared__ short Ks[128 * 64];
  __shared__ short Vt[64 * 128];
  __shared__ short Ps[64 * 128];

  const int tid = threadIdx.x;
  const int wave = tid >> 6, lane = tid & 63;
  const int g = lane >> 4, r = lane & 15;
  const size_t bbase = (size_t)bb * 8192;

  #pragma unroll
  for (int t = 0; t < 2; ++t) {
    int i = wave * 128 + t * 64 + lane;
    int row = i >> 3, seg = i & 7;
    int sseg = seg ^ (row & 7);
    const short* gp = qkv + (bbase + win * 64 + row) * 3072 + h * 64 + sseg * 8;
    async_ld16(&Qs[(wave * 128 + t * 64) * 8], gp);
  }
  #pragma unroll
  for (int t = 0; t < 4; ++t) {
    int i = wave * 256 + t * 64 + lane;
    int row = i >> 3, seg = i & 7;
    int sseg = seg ^ (row & 7);
    int kpos = win * 64 - 64 + row; if (kpos < 0) kpos = 0;
    const short* gp = qkv + (bbase + kpos) * 3072 + 1024 + h * 64 + sseg * 8;
    async_ld16(&Ks[(wave * 256 + t * 64) * 8], gp);
  }
  #pragma unroll
  for (int t = 0; t < 4; ++t) {
    int task = tid + t * 256;
    int j = task >> 3, dseg = task & 7;
    int kpos = win * 64 - 64 + j; if (kpos < 0) kpos = 0;
    bf16x8 v = *(const bf16x8*)(qkv + (bbase + kpos) * 3072 + 2048 + h * 64 + dseg * 8);
    #pragma unroll
    for (int e = 0; e < 8; ++e) {
      int d = dseg * 8 + e;
      Vt[d * 128 + (((j >> 3) ^ (d & 15)) * 8) + (j & 7)] = v[e];
    }
  }
  __syncthreads();

  f32x4 sac[8];
  #pragma unroll
  for (int n = 0; n < 8; ++n)
    #pragma unroll
    for (int e = 0; e < 4; ++e) sac[n][e] = 0.0f;
  {
    bf16x8 aq[2];
    #pragma unroll
    for (int ks = 0; ks < 2; ++ks) {
      int row = wave * 16 + r;
      aq[ks] = *(const bf16x8*)&Qs[row * 64 + (((ks * 4 + g) ^ (row & 7)) * 8)];
    }
    #pragma unroll
    for (int n = 0; n < 8; ++n)
      #pragma unroll
      for (int ks = 0; ks < 2; ++ks) {
        int key = n * 16 + r;
        bf16x8 bk = *(const bf16x8*)&Ks[key * 64 + (((ks * 4 + g) ^ (key & 7)) * 8)];
        sac[n] = __builtin_amdgcn_mfma_f32_16x16x32_bf16(aq[ks], bk, sac[n], 0, 0, 0);
      }
  }

  float pm[8][4], mx[4], sm[4];
  #pragma unroll
  for (int q = 0; q < 4; ++q) mx[q] = -3.0e38f;
  #pragma unroll
  for (int n = 0; n < 8; ++n)
    #pragma unroll
    for (int q = 0; q < 4; ++q) {
      int iq = wave * 16 + g * 4 + q;
      int j = n * 16 + r;
      bool ok = (j >= iq) && (j <= iq + 64) && (win > 0 || j >= 64);
      float s = ok ? sac[n][q] * 0.125f : -3.0e38f;
      pm[n][q] = s;
      mx[q] = fmaxf(mx[q], s);
    }
  #pragma unroll
  for (int q = 0; q < 4; ++q)
    #pragma unroll
    for (int off = 1; off < 16; off <<= 1) mx[q] = fmaxf(mx[q], __shfl_xor(mx[q], off));
  #pragma unroll
  for (int q = 0; q < 4; ++q) sm[q] = 0.0f;
  #pragma unroll
  for (int n = 0; n < 8; ++n)
    #pragma unroll
    for (int q = 0; q < 4; ++q) {
      float p = __expf(pm[n][q] - mx[q]);
      pm[n][q] = p;
      sm[q] += p;
    }
  #pragma unroll
  for (int q = 0; q < 4; ++q) {
    #pragma unroll
    for (int off = 1; off < 16; off <<= 1) sm[q] += __shfl_xor(sm[q], off);
    sm[q] = 1.0f / sm[q];
  }
  #pragma unroll
  for (int n = 0; n < 8; ++n)
    #pragma unroll
    for (int q = 0; q < 4; ++q) {
      int iq = wave * 16 + g * 4 + q;
      int j = n * 16 + r;
      Ps[iq * 128 + (((j >> 3) ^ (iq & 15)) * 8) + (j & 7)] = f2bf(pm[n][q] * sm[q]);
    }
  __syncthreads();

  f32x4 oac[4];
  #pragma unroll
  for (int n = 0; n < 4; ++n)
    #pragma unroll
    for (int e = 0; e < 4; ++e) oac[n][e] = 0.0f;
  #pragma unroll
  for (int ks = 0; ks < 4; ++ks) {
    int rowp = wave * 16 + r;
    bf16x8 ap = *(const bf16x8*)&Ps[rowp * 128 + (((ks * 4 + g) ^ (rowp & 15)) * 8)];
    #pragma unroll
    for (int n = 0; n < 4; ++n) {
      int d = n * 16 + r;
      bf16x8 bv = *(const bf16x8*)&Vt[d * 128 + (((ks * 4 + g) ^ (d & 15)) * 8)];
      oac[n] = __builtin_amdgcn_mfma_f32_16x16x32_bf16(ap, bv, oac[n], 0, 0, 0);
    }
  }
  #pragma unroll
  for (int n = 0; n < 4; ++n)
    #pragma unroll
    for (int q = 0; q < 4; ++q) {
      int iq = wave * 16 + g * 4 + q;
      int d = n * 16 + r;
      int pos = win * 64 + iq;
      aout[(bbase + pos) * 1024 + h * 64 + d] = f2bf(oac[n][q]);
    }
}

extern "C" void kernel_launch(void* const* d_in, const int* in_sizes, int n_in,
                              void* d_out, int out_size, void* d_ws, size_t ws_size,
                              hipStream_t stream) {
  const float* x      = (const float*)d_in[0];
  const float* w_norm = (const float*)d_in[1];
  const float* w_qkv  = (const float*)d_in[2];
  const float* w_o    = (const float*)d_in[3];
  float* out = (float*)d_out;
  (void)in_sizes; (void)n_in; (void)out_size; (void)ws_size;

  const int R = 4 * 8192;  // 32768 rows

  char* ws = (char*)d_ws;
  size_t off = 0;
  auto alloc = [&](size_t bytes) { char* p = ws + off; off += (bytes + 255) & ~(size_t)255; return p; };
  short* xn   = (short*)alloc((size_t)R * 1024 * 2);
  short* wqT  = (short*)alloc((size_t)3072 * 1024 * 2);
  short* woT  = (short*)alloc((size_t)1024 * 1024 * 2);
  short* qkv  = (short*)alloc((size_t)R * 3072 * 2);
  short* aout = (short*)alloc((size_t)R * 1024 * 2);
  float* ct   = (float*)alloc((size_t)8192 * 32 * 4);
  float* st   = (float*)alloc((size_t)8192 * 32 * 4);

  k_trig<<<1024, 256, 0, stream>>>(ct, st);
  k_transpose_cvt<<<dim3(3072 / 64, 1024 / 64), 256, 0, stream>>>(w_qkv, wqT, 1024, 3072);
  k_transpose_cvt<<<dim3(1024 / 64, 1024 / 64), 256, 0, stream>>>(w_o, woT, 1024, 1024);
  k_rmsnorm<<<R, 256, 0, stream>>>(x, w_norm, xn);
  k_gemm2<true, true><<<(R / 256) * (3072 / 256), 512, 0, stream>>>(xn, wqT, qkv, ct, st, R, 3072, 1024);
  k_attn<<<dim3(128, 16, 4), 256, 0, stream>>>(qkv, aout);
  k_gemm2<false, false><<<(R / 256) * (1024 / 256), 512, 0, stream>>>(aout, woT, out, ct, st, R, 1024, 1024);
}